// Round 10
// baseline (1410.221 us; speedup 1.0000x reference)
//
#include <hip/hip_runtime.h>
#include <cstdint>
#include <cstddef>

#define N_NODES 100000
#define N_EDGES 1600000
#define HD 128
#define OUTC 64
#define WDIM 512
#define RANKK 10
#define SLOPE 0.01f

typedef __attribute__((ext_vector_type(8))) short bf16x8;
typedef __attribute__((ext_vector_type(4))) float f32x4;

static __device__ __forceinline__ float lrelu(float v){ return v >= 0.f ? v : SLOPE*v; }
static __device__ __forceinline__ uint32_t bf16rne(float f){
  uint32_t b = __float_as_uint(f);
  return (b + 0x7FFFu + ((b >> 16) & 1u)) >> 16;
}

// ---------------- styles ----------------
__global__ void k_styles(const float* __restrict__ w,
                         const float* __restrict__ a0w, const float* __restrict__ a0b,
                         const float* __restrict__ a1w, const float* __restrict__ a1b,
                         float* __restrict__ st0, float* __restrict__ st1){
  int j = blockIdx.x*blockDim.x + threadIdx.x;
  if (j < 2560){
    float s = a0b[j];
    for (int k=0;k<WDIM;k++) s += w[k]*a0w[k*2560 + j];
    st0[j] = s;
  } else if (j < 2560+1920){
    int jj = j - 2560;
    float s = a1b[jj];
    for (int k=0;k<WDIM;k++) s += w[WDIM + k]*a1w[k*1920 + jj];
    st1[jj] = s;
  }
}

// ---------------- modulated + row-normalized weight, stored TRANSPOSED: wt[k][n] ----
__global__ void k_wmod(const float* __restrict__ st, const float* __restrict__ wgt,
                       float* __restrict__ wt, int c_out){
  int o = blockIdx.x, i = threadIdx.x;
  float mod = 0.f;
  #pragma unroll
  for (int r=0;r<RANKK;r++) mod += st[o*RANKK + r] * st[c_out*RANKK + r*HD + i];
  mod *= 0.31622776601683794f;
  float wv = wgt[o*HD + i] * (mod + 1.f);
  float sq = wv*wv;
  #pragma unroll
  for (int d=1; d<64; d<<=1) sq += __shfl_xor(sq, d, 64);
  __shared__ float red[2];
  if ((i & 63) == 0) red[i>>6] = sq;
  __syncthreads();
  float norm = sqrtf(red[0] + red[1]) + 1e-8f;
  wt[i*c_out + o] = wv / norm;
}

// ---------------- M2 = node_w @ (I + cat2) ; biasv = cat1_b + cat2_b + node_b@(I+cat2)
__global__ void k_m2bias(const float* __restrict__ node_w, const float* __restrict__ node_b,
                         const float* __restrict__ cat2_w, const float* __restrict__ cat1_b,
                         const float* __restrict__ cat2_b,
                         float* __restrict__ M2, float* __restrict__ biasv){
  int i = threadIdx.x;
  int k = blockIdx.x;
  if (k < HD){
    float s = node_w[k*HD + i];
    for (int j=0;j<HD;j++) s += node_w[k*HD + j]*cat2_w[j*HD + i];
    M2[k*HD + i] = s;
  } else {
    float s = cat1_b[i] + cat2_b[i] + node_b[i];
    for (int j=0;j<HD;j++) s += node_b[j]*cat2_w[j*HD + i];
    biasv[i] = s;
  }
}

// ---------------- pack B [K][Ncols] f32 -> bf16 MFMA fragments ----------------
__global__ void k_pack(const float* __restrict__ src, int K, int Ncols, int addI,
                       uint32_t* __restrict__ dst){
  int KTn = K >> 5;
  int kt = blockIdx.x % KTn, nt = blockIdx.x / KTn;
  int lane = threadIdx.x;
  int col = nt*16 + (lane & 15);
  uint32_t o[4];
  #pragma unroll
  for (int jj=0;jj<4;jj++){
    int k0 = kt*32 + (lane>>4)*8 + 2*jj;
    float v0 = src[(size_t)k0*Ncols + col]     + ((addI && k0   == col) ? 1.f : 0.f);
    float v1 = src[(size_t)(k0+1)*Ncols + col] + ((addI && k0+1 == col) ? 1.f : 0.f);
    o[jj] = bf16rne(v0) | (bf16rne(v1) << 16);
  }
  ((uint4*)dst)[blockIdx.x*64 + lane] = make_uint4(o[0], o[1], o[2], o[3]);
}

// ---------------- elw f32 -> bf16 packed ----------------
__global__ void k_cvt(const float* __restrict__ elw, uint32_t* __restrict__ elwb){
  int i = blockIdx.x*blockDim.x + threadIdx.x;
  if (i < N_NODES*(HD/2)){
    float2 t = *(const float2*)&elw[(size_t)i*2];
    elwb[i] = bf16rne(t.x) | (bf16rne(t.y) << 16);
  }
}

// ---------------- gatherA: edge-parallel, original order, global f32 atomics ----------
// One edge per wave, 4 edges batched for MLP. ei/ew reads are wave-uniform broadcasts
// (coalesced across waves); elwb row reads are the real traffic; atomicAdd is
// fire-and-forget (no return -> no wait). E = 400K waves of TLP, no CSR, no sort.
__global__ __launch_bounds__(256) void k_gatherA(const int* __restrict__ ei,
                         const float* __restrict__ ew,
                         const uint32_t* __restrict__ elwb,
                         float* __restrict__ accf){
  int wv = (blockIdx.x * blockDim.x + threadIdx.x) >> 6;
  int lane = threadIdx.x & 63;
  int e0 = wv * 4;
  if (e0 >= N_EDGES) return;   // E % 4 == 0, no partial waves
  int s0 = ei[e0],   s1 = ei[e0+1],   s2 = ei[e0+2],   s3 = ei[e0+3];
  int d0 = ei[N_EDGES+e0], d1 = ei[N_EDGES+e0+1];
  int d2 = ei[N_EDGES+e0+2], d3 = ei[N_EDGES+e0+3];
  float w0 = ew[e0], w1 = ew[e0+1], w2 = ew[e0+2], w3 = ew[e0+3];
  uint32_t u0 = elwb[(size_t)s0*(HD/2) + lane];
  uint32_t u1 = elwb[(size_t)s1*(HD/2) + lane];
  uint32_t u2 = elwb[(size_t)s2*(HD/2) + lane];
  uint32_t u3 = elwb[(size_t)s3*(HD/2) + lane];
  atomicAdd(&accf[(size_t)d0*HD + 2*lane],     __uint_as_float(u0 << 16) * w0);
  atomicAdd(&accf[(size_t)d0*HD + 2*lane + 1], __uint_as_float(u0 & 0xFFFF0000u) * w0);
  atomicAdd(&accf[(size_t)d1*HD + 2*lane],     __uint_as_float(u1 << 16) * w1);
  atomicAdd(&accf[(size_t)d1*HD + 2*lane + 1], __uint_as_float(u1 & 0xFFFF0000u) * w1);
  atomicAdd(&accf[(size_t)d2*HD + 2*lane],     __uint_as_float(u2 << 16) * w2);
  atomicAdd(&accf[(size_t)d2*HD + 2*lane + 1], __uint_as_float(u2 & 0xFFFF0000u) * w2);
  atomicAdd(&accf[(size_t)d3*HD + 2*lane],     __uint_as_float(u3 << 16) * w3);
  atomicAdd(&accf[(size_t)d3*HD + 2*lane + 1], __uint_as_float(u3 & 0xFFFF0000u) * w3);
}

// ---------------- fused node chain via bf16 MFMA, hi/lo compensated A ----------------
// acc now f32 (hi/lo split in staging, like x) -> full-precision first GEMM operand.
__global__ __launch_bounds__(512, 4) void k_fused(
    const float* __restrict__ accf, const float* __restrict__ x,
    const float* __restrict__ elb,
    const uint32_t* __restrict__ B1pk, const uint32_t* __restrict__ B2pk,
    const uint32_t* __restrict__ B3pk, const uint32_t* __restrict__ B4pk,
    const float* __restrict__ biasv, const float* __restrict__ sb0,
    const float* __restrict__ sb1, float* __restrict__ outp){
  __shared__ uint32_t lds[16384];                 // 64 KB
  short* sHi = (short*)lds;
  short* sLo = sHi + 16384;
  const int tid = threadIdx.x;
  const int lane = tid & 63, wid = tid >> 6;
  const int l15 = lane & 15, l4 = lane >> 4;
  const int wr = wid >> 2, wc = wid & 3;
  const int row0 = blockIdx.x * HD;

  // ---- stage accf (f32 + elb bias) -> hi/lo ----
  #pragma unroll
  for (int p=0;p<8;p++){
    int idx = tid + p*512;
    int r = idx >> 5, half = idx & 31;
    int slot = half >> 1, h4 = (half & 1) * 4;
    float4 v = make_float4(0.f,0.f,0.f,0.f);
    if (row0 + r < N_NODES) v = ((const float4*)accf)[(size_t)(row0+r)*32 + half];
    float4 bb = ((const float4*)elb)[half];
    v.x += bb.x; v.y += bb.y; v.z += bb.z; v.w += bb.w;
    uint hx = bf16rne(v.x), hy = bf16rne(v.y), hz = bf16rne(v.z), hw = bf16rne(v.w);
    uint lx = bf16rne(v.x - __uint_as_float(hx<<16));
    uint ly = bf16rne(v.y - __uint_as_float(hy<<16));
    uint lz = bf16rne(v.z - __uint_as_float(hz<<16));
    uint lw = bf16rne(v.w - __uint_as_float(hw<<16));
    int base = r*128 + ((slot ^ (r & 15)) << 3) + h4;
    *(uint2*)&sHi[base] = make_uint2(hx | (hy<<16), hz | (hw<<16));
    *(uint2*)&sLo[base] = make_uint2(lx | (ly<<16), lz | (lw<<16));
  }
  __syncthreads();

  // ---- phase 1: acc @ (I+cat1), hi+lo ----
  f32x4 acc[4][2];
  #pragma unroll
  for (int rt=0;rt<4;rt++)
    #pragma unroll
    for (int ct=0;ct<2;ct++) acc[rt][ct] = (f32x4){0.f,0.f,0.f,0.f};
  #pragma unroll
  for (int kt=0;kt<4;kt++){
    int aslot = ((kt*4 + l4) ^ l15) << 3;
    bf16x8 b0 = ((const bf16x8*)B1pk)[((wc*2+0)*4 + kt)*64 + lane];
    bf16x8 b1 = ((const bf16x8*)B1pk)[((wc*2+1)*4 + kt)*64 + lane];
    #pragma unroll
    for (int rt=0;rt<4;rt++){
      int abase = (wr*64 + rt*16 + l15)*128 + aslot;
      bf16x8 ah = *(const bf16x8*)&sHi[abase];
      bf16x8 al = *(const bf16x8*)&sLo[abase];
      acc[rt][0] = __builtin_amdgcn_mfma_f32_16x16x32_bf16(ah, b0, acc[rt][0], 0,0,0);
      acc[rt][1] = __builtin_amdgcn_mfma_f32_16x16x32_bf16(ah, b1, acc[rt][1], 0,0,0);
      acc[rt][0] = __builtin_amdgcn_mfma_f32_16x16x32_bf16(al, b0, acc[rt][0], 0,0,0);
      acc[rt][1] = __builtin_amdgcn_mfma_f32_16x16x32_bf16(al, b1, acc[rt][1], 0,0,0);
    }
  }
  __syncthreads();

  // ---- stage x (f32 -> hi/lo) ----
  #pragma unroll
  for (int p=0;p<8;p++){
    int idx = tid + p*512;
    int r = idx >> 5, half = idx & 31;
    int slot = half >> 1, h4 = (half & 1) * 4;
    float4 v = make_float4(0.f,0.f,0.f,0.f);
    if (row0 + r < N_NODES) v = ((const float4*)x)[(size_t)(row0+r)*32 + half];
    uint hx = bf16rne(v.x), hy = bf16rne(v.y), hz = bf16rne(v.z), hw = bf16rne(v.w);
    uint lx = bf16rne(v.x - __uint_as_float(hx<<16));
    uint ly = bf16rne(v.y - __uint_as_float(hy<<16));
    uint lz = bf16rne(v.z - __uint_as_float(hz<<16));
    uint lw = bf16rne(v.w - __uint_as_float(hw<<16));
    int base = r*128 + ((slot ^ (r & 15)) << 3) + h4;
    *(uint2*)&sHi[base] = make_uint2(hx | (hy<<16), hz | (hw<<16));
    *(uint2*)&sLo[base] = make_uint2(lx | (ly<<16), lz | (lw<<16));
  }
  __syncthreads();

  // ---- phase 2: + x @ M2 (hi+lo) ----
  #pragma unroll
  for (int kt=0;kt<4;kt++){
    int aslot = ((kt*4 + l4) ^ l15) << 3;
    bf16x8 b0 = ((const bf16x8*)B2pk)[((wc*2+0)*4 + kt)*64 + lane];
    bf16x8 b1 = ((const bf16x8*)B2pk)[((wc*2+1)*4 + kt)*64 + lane];
    #pragma unroll
    for (int rt=0;rt<4;rt++){
      int abase = (wr*64 + rt*16 + l15)*128 + aslot;
      bf16x8 ah = *(const bf16x8*)&sHi[abase];
      bf16x8 al = *(const bf16x8*)&sLo[abase];
      acc[rt][0] = __builtin_amdgcn_mfma_f32_16x16x32_bf16(ah, b0, acc[rt][0], 0,0,0);
      acc[rt][1] = __builtin_amdgcn_mfma_f32_16x16x32_bf16(ah, b1, acc[rt][1], 0,0,0);
      acc[rt][0] = __builtin_amdgcn_mfma_f32_16x16x32_bf16(al, b0, acc[rt][0], 0,0,0);
      acc[rt][1] = __builtin_amdgcn_mfma_f32_16x16x32_bf16(al, b1, acc[rt][1], 0,0,0);
    }
  }
  __syncthreads();

  // ---- epilogue p2: +biasv, lrelu, write out2 hi/lo to LDS ----
  #pragma unroll
  for (int ct=0;ct<2;ct++){
    int col = wc*32 + ct*16 + l15;
    float bb = biasv[col];
    int slotE = (col >> 3), elem = col & 7;
    #pragma unroll
    for (int rt=0;rt<4;rt++)
      #pragma unroll
      for (int rg=0;rg<4;rg++){
        int r = wr*64 + rt*16 + l4*4 + rg;
        float v = lrelu(acc[rt][ct][rg] + bb);
        uint h = bf16rne(v);
        uint l = bf16rne(v - __uint_as_float(h<<16));
        int sa = r*128 + ((slotE ^ (r & 15)) << 3) + elem;
        sHi[sa] = (short)h; sLo[sa] = (short)l;
      }
  }
  __syncthreads();

  // ---- phase 3: out2 @ W0T (hi+lo) ----
  #pragma unroll
  for (int rt=0;rt<4;rt++)
    #pragma unroll
    for (int ct=0;ct<2;ct++) acc[rt][ct] = (f32x4){0.f,0.f,0.f,0.f};
  #pragma unroll
  for (int kt=0;kt<4;kt++){
    int aslot = ((kt*4 + l4) ^ l15) << 3;
    bf16x8 b0 = ((const bf16x8*)B3pk)[((wc*2+0)*4 + kt)*64 + lane];
    bf16x8 b1 = ((const bf16x8*)B3pk)[((wc*2+1)*4 + kt)*64 + lane];
    #pragma unroll
    for (int rt=0;rt<4;rt++){
      int abase = (wr*64 + rt*16 + l15)*128 + aslot;
      bf16x8 ah = *(const bf16x8*)&sHi[abase];
      bf16x8 al = *(const bf16x8*)&sLo[abase];
      acc[rt][0] = __builtin_amdgcn_mfma_f32_16x16x32_bf16(ah, b0, acc[rt][0], 0,0,0);
      acc[rt][1] = __builtin_amdgcn_mfma_f32_16x16x32_bf16(ah, b1, acc[rt][1], 0,0,0);
      acc[rt][0] = __builtin_amdgcn_mfma_f32_16x16x32_bf16(al, b0, acc[rt][0], 0,0,0);
      acc[rt][1] = __builtin_amdgcn_mfma_f32_16x16x32_bf16(al, b1, acc[rt][1], 0,0,0);
    }
  }
  __syncthreads();

  // ---- epilogue p3: +sb0, lrelu, write h hi/lo ----
  #pragma unroll
  for (int ct=0;ct<2;ct++){
    int col = wc*32 + ct*16 + l15;
    float bb = sb0[col];
    int slotE = (col >> 3), elem = col & 7;
    #pragma unroll
    for (int rt=0;rt<4;rt++)
      #pragma unroll
      for (int rg=0;rg<4;rg++){
        int r = wr*64 + rt*16 + l4*4 + rg;
        float v = lrelu(acc[rt][ct][rg] + bb);
        uint h = bf16rne(v);
        uint l = bf16rne(v - __uint_as_float(h<<16));
        int sa = r*128 + ((slotE ^ (r & 15)) << 3) + elem;
        sHi[sa] = (short)h; sLo[sa] = (short)l;
      }
  }
  __syncthreads();

  // ---- phase 4: h @ W1T (64 cols) ----
  f32x4 y[4];
  #pragma unroll
  for (int ct=0;ct<4;ct++) y[ct] = (f32x4){0.f,0.f,0.f,0.f};
  #pragma unroll
  for (int kt=0;kt<4;kt++){
    int abase = (wid*16 + l15)*128 + (((kt*4 + l4) ^ l15) << 3);
    bf16x8 ah = *(const bf16x8*)&sHi[abase];
    bf16x8 al = *(const bf16x8*)&sLo[abase];
    #pragma unroll
    for (int ct=0;ct<4;ct++){
      bf16x8 b = ((const bf16x8*)B4pk)[(ct*4 + kt)*64 + lane];
      y[ct] = __builtin_amdgcn_mfma_f32_16x16x32_bf16(ah, b, y[ct], 0,0,0);
      y[ct] = __builtin_amdgcn_mfma_f32_16x16x32_bf16(al, b, y[ct], 0,0,0);
    }
  }
  __syncthreads();

  float* sOut = (float*)lds;
  #pragma unroll
  for (int ct=0;ct<4;ct++){
    int col = ct*16 + l15;
    float bb = sb1[col];
    #pragma unroll
    for (int rg=0;rg<4;rg++){
      int r = wid*16 + l4*4 + rg;
      sOut[r*OUTC + col] = lrelu(y[ct][rg] + bb);
    }
  }
  __syncthreads();
  #pragma unroll
  for (int p=0;p<4;p++){
    int o = tid + p*512;
    int r = o >> 4;
    if (row0 + r < N_NODES)
      ((float4*)outp)[(size_t)(row0+r)*16 + (o & 15)] = ((const float4*)sOut)[o];
  }
}

extern "C" void kernel_launch(void* const* d_in, const int* in_sizes, int n_in,
                              void* d_out, int out_size, void* d_ws, size_t ws_size,
                              hipStream_t stream){
  const float* x      = (const float*)d_in[0];
  const int*   ei     = (const int*)d_in[1];
  const float* ew     = (const float*)d_in[2];
  const float* w      = (const float*)d_in[3];
  const float* elw    = (const float*)d_in[4];
  const float* elb    = (const float*)d_in[5];
  const float* node_w = (const float*)d_in[6];
  const float* node_b = (const float*)d_in[7];
  const float* cat1_w = (const float*)d_in[8];
  const float* cat1_b = (const float*)d_in[9];
  const float* cat2_w = (const float*)d_in[10];
  const float* cat2_b = (const float*)d_in[11];
  const float* a0w    = (const float*)d_in[12];
  const float* a0b    = (const float*)d_in[13];
  const float* syn0_w = (const float*)d_in[14];
  const float* syn0_b = (const float*)d_in[15];
  const float* a1w    = (const float*)d_in[16];
  const float* a1b    = (const float*)d_in[17];
  const float* syn1_w = (const float*)d_in[18];
  const float* syn1_b = (const float*)d_in[19];
  float* outp = (float*)d_out;

  uint32_t* wsu = (uint32_t*)d_ws;
  float*    accf = (float*)wsu;                            // N*128 f32 (51.2MB)
  uint32_t* elwb = (uint32_t*)(accf + (size_t)N_NODES*HD); // N*64 u32 (25.6MB)
  float* st0    = (float*)(elwb + (size_t)N_NODES*(HD/2)); // 2560
  float* st1    = st0 + 2560;                              // 1920
  float* M2     = st1 + 1920;                              // 128*128
  float* biasv  = M2 + HD*HD;                              // 128
  float* W0T    = biasv + HD;                              // 128*128
  float* W1T    = W0T + HD*HD;                             // 128*64
  uint32_t* B1pk = (uint32_t*)(W1T + HD*OUTC);             // 8192 u32
  uint32_t* B2pk = B1pk + 8192;
  uint32_t* B3pk = B2pk + 8192;
  uint32_t* B4pk = B3pk + 8192;                            // 4096 u32

  hipMemsetAsync(accf, 0, (size_t)N_NODES*HD*sizeof(float), stream);
  k_cvt<<<(N_NODES*(HD/2)+255)/256, 256, 0, stream>>>(elw, elwb);
  k_styles<<<(2560+1920+255)/256, 256, 0, stream>>>(w, a0w, a0b, a1w, a1b, st0, st1);
  k_wmod<<<HD, HD, 0, stream>>>(st0, syn0_w, W0T, HD);
  k_wmod<<<OUTC, HD, 0, stream>>>(st1, syn1_w, W1T, OUTC);
  k_m2bias<<<HD+1, HD, 0, stream>>>(node_w, node_b, cat2_w, cat1_b, cat2_b, M2, biasv);
  k_pack<<<32, 64, 0, stream>>>(cat1_w, HD, HD, 1, B1pk);
  k_pack<<<32, 64, 0, stream>>>(M2,    HD, HD, 0, B2pk);
  k_pack<<<32, 64, 0, stream>>>(W0T,   HD, HD, 0, B3pk);
  k_pack<<<16, 64, 0, stream>>>(W1T,   HD, OUTC, 0, B4pk);
  // edge scatter: 400K waves, 4 edges each, global f32 atomics
  k_gatherA<<<(N_EDGES/4*64)/256, 256, 0, stream>>>(ei, ew, elwb, accf);
  k_fused<<<(N_NODES+HD-1)/HD, 512, 0, stream>>>(accf, x, elb, B1pk, B2pk, B3pk, B4pk,
                                                 biasv, syn0_b, syn1_b, outp);
}

// Round 11
// 337.911 us; speedup vs baseline: 4.1733x; 4.1733x over previous
//
#include <hip/hip_runtime.h>
#include <cstdint>
#include <cstddef>

#define N_NODES 100000
#define N_EDGES 1600000
#define HD 128
#define OUTC 64
#define WDIM 512
#define RANKK 10
#define SLOPE 0.01f
#define SCAN_NBLK ((N_NODES + 1023)/1024)   // 98
#define FILL_BLOCKS 2048                     // 256 blocks per XCD

typedef __attribute__((ext_vector_type(8))) short bf16x8;
typedef __attribute__((ext_vector_type(4))) float f32x4;

static __device__ __forceinline__ float lrelu(float v){ return v >= 0.f ? v : SLOPE*v; }
static __device__ __forceinline__ uint32_t bf16rne(float f){
  uint32_t b = __float_as_uint(f);
  return (b + 0x7FFFu + ((b >> 16) & 1u)) >> 16;
}

// ---------------- styles ----------------
__global__ void k_styles(const float* __restrict__ w,
                         const float* __restrict__ a0w, const float* __restrict__ a0b,
                         const float* __restrict__ a1w, const float* __restrict__ a1b,
                         float* __restrict__ st0, float* __restrict__ st1){
  int j = blockIdx.x*blockDim.x + threadIdx.x;
  if (j < 2560){
    float s = a0b[j];
    for (int k=0;k<WDIM;k++) s += w[k]*a0w[k*2560 + j];
    st0[j] = s;
  } else if (j < 2560+1920){
    int jj = j - 2560;
    float s = a1b[jj];
    for (int k=0;k<WDIM;k++) s += w[WDIM + k]*a1w[k*1920 + jj];
    st1[jj] = s;
  }
}

// ---------------- modulated + row-normalized weight, stored TRANSPOSED: wt[k][n] ----
__global__ void k_wmod(const float* __restrict__ st, const float* __restrict__ wgt,
                       float* __restrict__ wt, int c_out){
  int o = blockIdx.x, i = threadIdx.x;
  float mod = 0.f;
  #pragma unroll
  for (int r=0;r<RANKK;r++) mod += st[o*RANKK + r] * st[c_out*RANKK + r*HD + i];
  mod *= 0.31622776601683794f;
  float wv = wgt[o*HD + i] * (mod + 1.f);
  float sq = wv*wv;
  #pragma unroll
  for (int d=1; d<64; d<<=1) sq += __shfl_xor(sq, d, 64);
  __shared__ float red[2];
  if ((i & 63) == 0) red[i>>6] = sq;
  __syncthreads();
  float norm = sqrtf(red[0] + red[1]) + 1e-8f;
  wt[i*c_out + o] = wv / norm;
}

// ---------------- M2 = node_w @ (I + cat2) ; biasv = cat1_b + cat2_b + node_b@(I+cat2)
__global__ void k_m2bias(const float* __restrict__ node_w, const float* __restrict__ node_b,
                         const float* __restrict__ cat2_w, const float* __restrict__ cat1_b,
                         const float* __restrict__ cat2_b,
                         float* __restrict__ M2, float* __restrict__ biasv){
  int i = threadIdx.x;
  int k = blockIdx.x;
  if (k < HD){
    float s = node_w[k*HD + i];
    for (int j=0;j<HD;j++) s += node_w[k*HD + j]*cat2_w[j*HD + i];
    M2[k*HD + i] = s;
  } else {
    float s = cat1_b[i] + cat2_b[i] + node_b[i];
    for (int j=0;j<HD;j++) s += node_b[j]*cat2_w[j*HD + i];
    biasv[i] = s;
  }
}

// ---------------- pack B [K][Ncols] f32 -> bf16 MFMA fragments ----------------
__global__ void k_pack(const float* __restrict__ src, int K, int Ncols, int addI,
                       uint32_t* __restrict__ dst){
  int KTn = K >> 5;
  int kt = blockIdx.x % KTn, nt = blockIdx.x / KTn;
  int lane = threadIdx.x;
  int col = nt*16 + (lane & 15);
  uint32_t o[4];
  #pragma unroll
  for (int jj=0;jj<4;jj++){
    int k0 = kt*32 + (lane>>4)*8 + 2*jj;
    float v0 = src[(size_t)k0*Ncols + col]     + ((addI && k0   == col) ? 1.f : 0.f);
    float v1 = src[(size_t)(k0+1)*Ncols + col] + ((addI && k0+1 == col) ? 1.f : 0.f);
    o[jj] = bf16rne(v0) | (bf16rne(v1) << 16);
  }
  ((uint4*)dst)[blockIdx.x*64 + lane] = make_uint4(o[0], o[1], o[2], o[3]);
}

// ---------------- elw f32 -> bf16 packed ----------------
__global__ void k_cvt(const float* __restrict__ elw, uint32_t* __restrict__ elwb){
  int i = blockIdx.x*blockDim.x + threadIdx.x;
  if (i < N_NODES*(HD/2)){
    float2 t = *(const float2*)&elw[(size_t)i*2];
    elwb[i] = bf16rne(t.x) | (bf16rne(t.y) << 16);
  }
}

// ---------------- CSR build ----------------
__global__ void k_hist(const int* __restrict__ ei, int* __restrict__ cnt){
  int e = blockIdx.x*blockDim.x + threadIdx.x;
  if (e < N_EDGES) atomicAdd(&cnt[ei[N_EDGES + e]], 1);
}

__global__ __launch_bounds__(1024) void k_scanA(const int* __restrict__ cnt,
                                                int* __restrict__ rowptr,
                                                int* __restrict__ partials){
  __shared__ int sh[1024];
  int tid = threadIdx.x;
  int gi = blockIdx.x*1024 + tid;
  int v = (gi < N_NODES) ? cnt[gi] : 0;
  sh[tid] = v;
  __syncthreads();
  #pragma unroll
  for (int off=1; off<1024; off<<=1){
    int t = (tid >= off) ? sh[tid-off] : 0;
    __syncthreads();
    sh[tid] += t;
    __syncthreads();
  }
  if (gi < N_NODES) rowptr[gi] = sh[tid] - v;
  if (tid == 1023) partials[blockIdx.x] = sh[1023];
}

__global__ __launch_bounds__(128) void k_scanB(int* __restrict__ partials){
  __shared__ int sh[128];
  int tid = threadIdx.x;
  int v = (tid < SCAN_NBLK) ? partials[tid] : 0;
  sh[tid] = v;
  __syncthreads();
  #pragma unroll
  for (int off=1; off<128; off<<=1){
    int t = (tid >= off) ? sh[tid-off] : 0;
    __syncthreads();
    sh[tid] += t;
    __syncthreads();
  }
  if (tid < SCAN_NBLK) partials[tid] = sh[tid] - v;
  if (tid == 127) partials[SCAN_NBLK] = sh[127];
}

__global__ __launch_bounds__(1024) void k_scanC(const int* __restrict__ partials,
                                                int* __restrict__ rowptr,
                                                int* __restrict__ cursor){
  int gi = blockIdx.x*1024 + threadIdx.x;
  if (gi < N_NODES){
    int r = rowptr[gi] + partials[blockIdx.x];
    rowptr[gi] = r;
    cursor[gi] = r;
  } else if (gi == N_NODES){
    rowptr[N_NODES] = partials[SCAN_NBLK];
  }
}

// ---------------- fill: XCD-sliced scatter (fixes 8.75x write amplification) ----------
// Block b runs on XCD b%8 (round-robin dispatch). Each XCD's 256 blocks scan ALL edges
// but write only dsts in their 1/8 node-slice -> every epair/cursor line is written by
// ONE XCD; the 1.6MB slice fits its private 4MB L2, partial 8B writes merge before
// writeback. ei re-reads (8x) come from L2/L3 (R7: ei was cache-resident, FETCH 9.9MB).
__global__ __launch_bounds__(256) void k_fill(const int* __restrict__ ei,
                                              const float* __restrict__ ew,
                                              int* __restrict__ cursor,
                                              int2* __restrict__ epair){
  const int xcd = blockIdx.x & 7;
  const int lo = (int)((long long)N_NODES * xcd >> 3);
  const int hi = (int)((long long)N_NODES * (xcd+1) >> 3);
  const int bslot = blockIdx.x >> 3;           // 0..255 within this XCD
  const int stride = (FILL_BLOCKS >> 3) * 256; // 65536 threads per XCD
  for (int e = bslot*256 + threadIdx.x; e < N_EDGES; e += stride){
    int d = ei[N_EDGES + e];
    if (d >= lo && d < hi){
      int pos = atomicAdd(&cursor[d], 1);
      epair[pos] = make_int2(ei[e], __float_as_int(ew[e]));
    }
  }
}

// ---------------- gather: node-per-wave, register accumulate, 4-deep MLP unroll ----
__global__ __launch_bounds__(256) void k_gather(const int* __restrict__ rowptr,
                         const int2* __restrict__ epair,
                         const uint32_t* __restrict__ elwb, const float* __restrict__ elb,
                         uint32_t* __restrict__ accbb){
  int wid = (blockIdx.x * blockDim.x + threadIdx.x) >> 6;
  int lane = threadIdx.x & 63;
  if (wid >= N_NODES) return;
  int beg = rowptr[wid], end = rowptr[wid+1];
  float sx = 0.f, sy = 0.f;
  int e = beg;
  for (; e + 4 <= end; e += 4){
    int2 p0 = epair[e], p1 = epair[e+1], p2 = epair[e+2], p3 = epair[e+3];
    uint32_t u0 = elwb[(size_t)p0.x*(HD/2) + lane];
    uint32_t u1 = elwb[(size_t)p1.x*(HD/2) + lane];
    uint32_t u2 = elwb[(size_t)p2.x*(HD/2) + lane];
    uint32_t u3 = elwb[(size_t)p3.x*(HD/2) + lane];
    float w0 = __int_as_float(p0.y), w1 = __int_as_float(p1.y);
    float w2 = __int_as_float(p2.y), w3 = __int_as_float(p3.y);
    sx += __uint_as_float(u0 << 16) * w0;
    sy += __uint_as_float(u0 & 0xFFFF0000u) * w0;
    sx += __uint_as_float(u1 << 16) * w1;
    sy += __uint_as_float(u1 & 0xFFFF0000u) * w1;
    sx += __uint_as_float(u2 << 16) * w2;
    sy += __uint_as_float(u2 & 0xFFFF0000u) * w2;
    sx += __uint_as_float(u3 << 16) * w3;
    sy += __uint_as_float(u3 & 0xFFFF0000u) * w3;
  }
  for (; e < end; ++e){
    int2 p = epair[e];
    float wv = __int_as_float(p.y);
    uint32_t u = elwb[(size_t)p.x*(HD/2) + lane];
    sx += __uint_as_float(u << 16) * wv;
    sy += __uint_as_float(u & 0xFFFF0000u) * wv;
  }
  sx += elb[lane*2]; sy += elb[lane*2+1];
  accbb[(size_t)wid*(HD/2) + lane] = bf16rne(sx) | (bf16rne(sy) << 16);
}

// ---------------- fused node chain via bf16 MFMA, hi/lo compensated A ----------------
__global__ __launch_bounds__(512, 4) void k_fused(
    const uint32_t* __restrict__ accbb, const float* __restrict__ x,
    const uint32_t* __restrict__ B1pk, const uint32_t* __restrict__ B2pk,
    const uint32_t* __restrict__ B3pk, const uint32_t* __restrict__ B4pk,
    const float* __restrict__ biasv, const float* __restrict__ sb0,
    const float* __restrict__ sb1, float* __restrict__ outp){
  __shared__ uint32_t lds[16384];                 // 64 KB
  short* sHi = (short*)lds;
  short* sLo = sHi + 16384;
  const int tid = threadIdx.x;
  const int lane = tid & 63, wid = tid >> 6;
  const int l15 = lane & 15, l4 = lane >> 4;
  const int wr = wid >> 2, wc = wid & 3;
  const int row0 = blockIdx.x * HD;

  #pragma unroll
  for (int p=0;p<4;p++){
    int idx = tid + p*512;
    int r = idx >> 4, slot = idx & 15;
    uint4 v = make_uint4(0,0,0,0);
    if (row0 + r < N_NODES) v = ((const uint4*)accbb)[(size_t)(row0+r)*16 + slot];
    *(uint4*)&sHi[r*128 + ((slot ^ (r & 15)) << 3)] = v;
  }
  __syncthreads();

  f32x4 acc[4][2];
  #pragma unroll
  for (int rt=0;rt<4;rt++)
    #pragma unroll
    for (int ct=0;ct<2;ct++) acc[rt][ct] = (f32x4){0.f,0.f,0.f,0.f};
  #pragma unroll
  for (int kt=0;kt<4;kt++){
    int aslot = ((kt*4 + l4) ^ l15) << 3;
    bf16x8 b0 = ((const bf16x8*)B1pk)[((wc*2+0)*4 + kt)*64 + lane];
    bf16x8 b1 = ((const bf16x8*)B1pk)[((wc*2+1)*4 + kt)*64 + lane];
    #pragma unroll
    for (int rt=0;rt<4;rt++){
      bf16x8 a = *(const bf16x8*)&sHi[(wr*64 + rt*16 + l15)*128 + aslot];
      acc[rt][0] = __builtin_amdgcn_mfma_f32_16x16x32_bf16(a, b0, acc[rt][0], 0,0,0);
      acc[rt][1] = __builtin_amdgcn_mfma_f32_16x16x32_bf16(a, b1, acc[rt][1], 0,0,0);
    }
  }
  __syncthreads();

  #pragma unroll
  for (int p=0;p<8;p++){
    int idx = tid + p*512;
    int r = idx >> 5, half = idx & 31;
    int slot = half >> 1, h4 = (half & 1) * 4;
    float4 v = make_float4(0.f,0.f,0.f,0.f);
    if (row0 + r < N_NODES) v = ((const float4*)x)[(size_t)(row0+r)*32 + half];
    uint hx = bf16rne(v.x), hy = bf16rne(v.y), hz = bf16rne(v.z), hw = bf16rne(v.w);
    uint lx = bf16rne(v.x - __uint_as_float(hx<<16));
    uint ly = bf16rne(v.y - __uint_as_float(hy<<16));
    uint lz = bf16rne(v.z - __uint_as_float(hz<<16));
    uint lw = bf16rne(v.w - __uint_as_float(hw<<16));
    int base = r*128 + ((slot ^ (r & 15)) << 3) + h4;
    *(uint2*)&sHi[base] = make_uint2(hx | (hy<<16), hz | (hw<<16));
    *(uint2*)&sLo[base] = make_uint2(lx | (ly<<16), lz | (lw<<16));
  }
  __syncthreads();

  #pragma unroll
  for (int kt=0;kt<4;kt++){
    int aslot = ((kt*4 + l4) ^ l15) << 3;
    bf16x8 b0 = ((const bf16x8*)B2pk)[((wc*2+0)*4 + kt)*64 + lane];
    bf16x8 b1 = ((const bf16x8*)B2pk)[((wc*2+1)*4 + kt)*64 + lane];
    #pragma unroll
    for (int rt=0;rt<4;rt++){
      int abase = (wr*64 + rt*16 + l15)*128 + aslot;
      bf16x8 ah = *(const bf16x8*)&sHi[abase];
      bf16x8 al = *(const bf16x8*)&sLo[abase];
      acc[rt][0] = __builtin_amdgcn_mfma_f32_16x16x32_bf16(ah, b0, acc[rt][0], 0,0,0);
      acc[rt][1] = __builtin_amdgcn_mfma_f32_16x16x32_bf16(ah, b1, acc[rt][1], 0,0,0);
      acc[rt][0] = __builtin_amdgcn_mfma_f32_16x16x32_bf16(al, b0, acc[rt][0], 0,0,0);
      acc[rt][1] = __builtin_amdgcn_mfma_f32_16x16x32_bf16(al, b1, acc[rt][1], 0,0,0);
    }
  }
  __syncthreads();

  #pragma unroll
  for (int ct=0;ct<2;ct++){
    int col = wc*32 + ct*16 + l15;
    float bb = biasv[col];
    int slotE = (col >> 3), elem = col & 7;
    #pragma unroll
    for (int rt=0;rt<4;rt++)
      #pragma unroll
      for (int rg=0;rg<4;rg++){
        int r = wr*64 + rt*16 + l4*4 + rg;
        float v = lrelu(acc[rt][ct][rg] + bb);
        uint h = bf16rne(v);
        uint l = bf16rne(v - __uint_as_float(h<<16));
        int sa = r*128 + ((slotE ^ (r & 15)) << 3) + elem;
        sHi[sa] = (short)h; sLo[sa] = (short)l;
      }
  }
  __syncthreads();

  #pragma unroll
  for (int rt=0;rt<4;rt++)
    #pragma unroll
    for (int ct=0;ct<2;ct++) acc[rt][ct] = (f32x4){0.f,0.f,0.f,0.f};
  #pragma unroll
  for (int kt=0;kt<4;kt++){
    int aslot = ((kt*4 + l4) ^ l15) << 3;
    bf16x8 b0 = ((const bf16x8*)B3pk)[((wc*2+0)*4 + kt)*64 + lane];
    bf16x8 b1 = ((const bf16x8*)B3pk)[((wc*2+1)*4 + kt)*64 + lane];
    #pragma unroll
    for (int rt=0;rt<4;rt++){
      int abase = (wr*64 + rt*16 + l15)*128 + aslot;
      bf16x8 ah = *(const bf16x8*)&sHi[abase];
      bf16x8 al = *(const bf16x8*)&sLo[abase];
      acc[rt][0] = __builtin_amdgcn_mfma_f32_16x16x32_bf16(ah, b0, acc[rt][0], 0,0,0);
      acc[rt][1] = __builtin_amdgcn_mfma_f32_16x16x32_bf16(ah, b1, acc[rt][1], 0,0,0);
      acc[rt][0] = __builtin_amdgcn_mfma_f32_16x16x32_bf16(al, b0, acc[rt][0], 0,0,0);
      acc[rt][1] = __builtin_amdgcn_mfma_f32_16x16x32_bf16(al, b1, acc[rt][1], 0,0,0);
    }
  }
  __syncthreads();

  #pragma unroll
  for (int ct=0;ct<2;ct++){
    int col = wc*32 + ct*16 + l15;
    float bb = sb0[col];
    int slotE = (col >> 3), elem = col & 7;
    #pragma unroll
    for (int rt=0;rt<4;rt++)
      #pragma unroll
      for (int rg=0;rg<4;rg++){
        int r = wr*64 + rt*16 + l4*4 + rg;
        float v = lrelu(acc[rt][ct][rg] + bb);
        uint h = bf16rne(v);
        uint l = bf16rne(v - __uint_as_float(h<<16));
        int sa = r*128 + ((slotE ^ (r & 15)) << 3) + elem;
        sHi[sa] = (short)h; sLo[sa] = (short)l;
      }
  }
  __syncthreads();

  f32x4 y[4];
  #pragma unroll
  for (int ct=0;ct<4;ct++) y[ct] = (f32x4){0.f,0.f,0.f,0.f};
  #pragma unroll
  for (int kt=0;kt<4;kt++){
    int abase = (wid*16 + l15)*128 + (((kt*4 + l4) ^ l15) << 3);
    bf16x8 ah = *(const bf16x8*)&sHi[abase];
    bf16x8 al = *(const bf16x8*)&sLo[abase];
    #pragma unroll
    for (int ct=0;ct<4;ct++){
      bf16x8 b = ((const bf16x8*)B4pk)[(ct*4 + kt)*64 + lane];
      y[ct] = __builtin_amdgcn_mfma_f32_16x16x32_bf16(ah, b, y[ct], 0,0,0);
      y[ct] = __builtin_amdgcn_mfma_f32_16x16x32_bf16(al, b, y[ct], 0,0,0);
    }
  }
  __syncthreads();

  float* sOut = (float*)lds;
  #pragma unroll
  for (int ct=0;ct<4;ct++){
    int col = ct*16 + l15;
    float bb = sb1[col];
    #pragma unroll
    for (int rg=0;rg<4;rg++){
      int r = wid*16 + l4*4 + rg;
      sOut[r*OUTC + col] = lrelu(y[ct][rg] + bb);
    }
  }
  __syncthreads();
  #pragma unroll
  for (int p=0;p<4;p++){
    int o = tid + p*512;
    int r = o >> 4;
    if (row0 + r < N_NODES)
      ((float4*)outp)[(size_t)(row0+r)*16 + (o & 15)] = ((const float4*)sOut)[o];
  }
}

extern "C" void kernel_launch(void* const* d_in, const int* in_sizes, int n_in,
                              void* d_out, int out_size, void* d_ws, size_t ws_size,
                              hipStream_t stream){
  const float* x      = (const float*)d_in[0];
  const int*   ei     = (const int*)d_in[1];
  const float* ew     = (const float*)d_in[2];
  const float* w      = (const float*)d_in[3];
  const float* elw    = (const float*)d_in[4];
  const float* elb    = (const float*)d_in[5];
  const float* node_w = (const float*)d_in[6];
  const float* node_b = (const float*)d_in[7];
  const float* cat1_w = (const float*)d_in[8];
  const float* cat1_b = (const float*)d_in[9];
  const float* cat2_w = (const float*)d_in[10];
  const float* cat2_b = (const float*)d_in[11];
  const float* a0w    = (const float*)d_in[12];
  const float* a0b    = (const float*)d_in[13];
  const float* syn0_w = (const float*)d_in[14];
  const float* syn0_b = (const float*)d_in[15];
  const float* a1w    = (const float*)d_in[16];
  const float* a1b    = (const float*)d_in[17];
  const float* syn1_w = (const float*)d_in[18];
  const float* syn1_b = (const float*)d_in[19];
  float* outp = (float*)d_out;

  uint32_t* wsu = (uint32_t*)d_ws;
  uint32_t* accbb = wsu;                                   // N*64 u32 (bf16x2)
  uint32_t* elwb  = accbb + (size_t)N_NODES*(HD/2);        // N*64 u32
  float* st0    = (float*)(elwb + (size_t)N_NODES*(HD/2)); // 2560
  float* st1    = st0 + 2560;                              // 1920
  float* M2     = st1 + 1920;                              // 128*128
  float* biasv  = M2 + HD*HD;                              // 128
  float* W0T    = biasv + HD;                              // 128*128
  float* W1T    = W0T + HD*HD;                             // 128*64
  uint32_t* B1pk = (uint32_t*)(W1T + HD*OUTC);             // 8192 u32
  uint32_t* B2pk = B1pk + 8192;
  uint32_t* B3pk = B2pk + 8192;
  uint32_t* B4pk = B3pk + 8192;                            // 4096 u32
  int*   cnt     = (int*)(B4pk + 4096);                    // N
  int*   rowptr  = cnt + N_NODES;                          // N+1
  int*   cursor  = rowptr + N_NODES + 1;                   // N
  int*   partials= cursor + N_NODES;                       // SCAN_NBLK+1
  int2*  epair   = (int2*)(partials + SCAN_NBLK + 2);      // E (8B aligned)

  hipMemsetAsync(cnt, 0, N_NODES*sizeof(int), stream);
  k_cvt<<<(N_NODES*(HD/2)+255)/256, 256, 0, stream>>>(elw, elwb);
  k_styles<<<(2560+1920+255)/256, 256, 0, stream>>>(w, a0w, a0b, a1w, a1b, st0, st1);
  k_wmod<<<HD, HD, 0, stream>>>(st0, syn0_w, W0T, HD);
  k_wmod<<<OUTC, HD, 0, stream>>>(st1, syn1_w, W1T, OUTC);
  k_m2bias<<<HD+1, HD, 0, stream>>>(node_w, node_b, cat2_w, cat1_b, cat2_b, M2, biasv);
  k_pack<<<32, 64, 0, stream>>>(cat1_w, HD, HD, 1, B1pk);
  k_pack<<<32, 64, 0, stream>>>(M2,    HD, HD, 0, B2pk);
  k_pack<<<32, 64, 0, stream>>>(W0T,   HD, HD, 0, B3pk);
  k_pack<<<16, 64, 0, stream>>>(W1T,   HD, OUTC, 0, B4pk);
  k_hist<<<(N_EDGES+255)/256, 256, 0, stream>>>(ei, cnt);
  k_scanA<<<SCAN_NBLK, 1024, 0, stream>>>(cnt, rowptr, partials);
  k_scanB<<<1, 128, 0, stream>>>(partials);
  k_scanC<<<SCAN_NBLK, 1024, 0, stream>>>(partials, rowptr, cursor);
  k_fill<<<FILL_BLOCKS, 256, 0, stream>>>(ei, ew, cursor, epair);
  k_gather<<<(N_NODES*64)/256, 256, 0, stream>>>(rowptr, epair, elwb, elb, accbb);
  k_fused<<<(N_NODES+HD-1)/HD, 512, 0, stream>>>(accbb, x, B1pk, B2pk, B3pk, B4pk,
                                                 biasv, syn0_b, syn1_b, outp);
}

// Round 12
// 257.998 us; speedup vs baseline: 5.4660x; 1.3097x over previous
//
#include <hip/hip_runtime.h>
#include <cstdint>
#include <cstddef>

#define N_NODES 100000
#define N_EDGES 1600000
#define HD 128
#define OUTC 64
#define WDIM 512
#define RANKK 10
#define SLOPE 0.01f
#define CAP 64                               // slots per node (mean degree 16)
#define FILL_BLOCKS 2048                     // 256 blocks per XCD

typedef __attribute__((ext_vector_type(8))) short bf16x8;
typedef __attribute__((ext_vector_type(4))) float f32x4;

static __device__ __forceinline__ float lrelu(float v){ return v >= 0.f ? v : SLOPE*v; }
static __device__ __forceinline__ uint32_t bf16rne(float f){
  uint32_t b = __float_as_uint(f);
  return (b + 0x7FFFu + ((b >> 16) & 1u)) >> 16;
}

// ---------------- styles ----------------
__global__ void k_styles(const float* __restrict__ w,
                         const float* __restrict__ a0w, const float* __restrict__ a0b,
                         const float* __restrict__ a1w, const float* __restrict__ a1b,
                         float* __restrict__ st0, float* __restrict__ st1){
  int j = blockIdx.x*blockDim.x + threadIdx.x;
  if (j < 2560){
    float s = a0b[j];
    for (int k=0;k<WDIM;k++) s += w[k]*a0w[k*2560 + j];
    st0[j] = s;
  } else if (j < 2560+1920){
    int jj = j - 2560;
    float s = a1b[jj];
    for (int k=0;k<WDIM;k++) s += w[WDIM + k]*a1w[k*1920 + jj];
    st1[jj] = s;
  }
}

// ---------------- modulated + row-normalized weight, stored TRANSPOSED: wt[k][n] ----
__global__ void k_wmod(const float* __restrict__ st, const float* __restrict__ wgt,
                       float* __restrict__ wt, int c_out){
  int o = blockIdx.x, i = threadIdx.x;
  float mod = 0.f;
  #pragma unroll
  for (int r=0;r<RANKK;r++) mod += st[o*RANKK + r] * st[c_out*RANKK + r*HD + i];
  mod *= 0.31622776601683794f;
  float wv = wgt[o*HD + i] * (mod + 1.f);
  float sq = wv*wv;
  #pragma unroll
  for (int d=1; d<64; d<<=1) sq += __shfl_xor(sq, d, 64);
  __shared__ float red[2];
  if ((i & 63) == 0) red[i>>6] = sq;
  __syncthreads();
  float norm = sqrtf(red[0] + red[1]) + 1e-8f;
  wt[i*c_out + o] = wv / norm;
}

// ---------------- M2 = node_w @ (I + cat2) ; biasv = cat1_b + cat2_b + node_b@(I+cat2)
__global__ void k_m2bias(const float* __restrict__ node_w, const float* __restrict__ node_b,
                         const float* __restrict__ cat2_w, const float* __restrict__ cat1_b,
                         const float* __restrict__ cat2_b,
                         float* __restrict__ M2, float* __restrict__ biasv){
  int i = threadIdx.x;
  int k = blockIdx.x;
  if (k < HD){
    float s = node_w[k*HD + i];
    for (int j=0;j<HD;j++) s += node_w[k*HD + j]*cat2_w[j*HD + i];
    M2[k*HD + i] = s;
  } else {
    float s = cat1_b[i] + cat2_b[i] + node_b[i];
    for (int j=0;j<HD;j++) s += node_b[j]*cat2_w[j*HD + i];
    biasv[i] = s;
  }
}

// ---------------- pack B [K][Ncols] f32 -> bf16 MFMA fragments ----------------
__global__ void k_pack(const float* __restrict__ src, int K, int Ncols, int addI,
                       uint32_t* __restrict__ dst){
  int KTn = K >> 5;
  int kt = blockIdx.x % KTn, nt = blockIdx.x / KTn;
  int lane = threadIdx.x;
  int col = nt*16 + (lane & 15);
  uint32_t o[4];
  #pragma unroll
  for (int jj=0;jj<4;jj++){
    int k0 = kt*32 + (lane>>4)*8 + 2*jj;
    float v0 = src[(size_t)k0*Ncols + col]     + ((addI && k0   == col) ? 1.f : 0.f);
    float v1 = src[(size_t)(k0+1)*Ncols + col] + ((addI && k0+1 == col) ? 1.f : 0.f);
    o[jj] = bf16rne(v0) | (bf16rne(v1) << 16);
  }
  ((uint4*)dst)[blockIdx.x*64 + lane] = make_uint4(o[0], o[1], o[2], o[3]);
}

// ---------------- elw f32 -> bf16 packed ----------------
__global__ void k_cvt(const float* __restrict__ elw, uint32_t* __restrict__ elwb){
  int i = blockIdx.x*blockDim.x + threadIdx.x;
  if (i < N_NODES*(HD/2)){
    float2 t = *(const float2*)&elw[(size_t)i*2];
    elwb[i] = bf16rne(t.x) | (bf16rne(t.y) << 16);
  }
}

// ---------------- fill: slotted CSR, XCD-sliced; no hist/scan needed ----------------
// slot payload: src(17 bits) | w-enc(15 bits: bf16 sans sign, RNE) << 17. w in [0,1) > 0.
// cnt[N_NODES] doubles as overflow counter.
__global__ __launch_bounds__(256) void k_fill(const int* __restrict__ ei,
                                              const float* __restrict__ ew,
                                              int* __restrict__ cnt,
                                              uint32_t* __restrict__ eslot,
                                              int* __restrict__ ovf){
  const int xcd = blockIdx.x & 7;
  const int lo = (int)((long long)N_NODES * xcd >> 3);
  const int hi = (int)((long long)N_NODES * (xcd+1) >> 3);
  const int bslot = blockIdx.x >> 3;
  const int stride = (FILL_BLOCKS >> 3) * 256;
  for (int e = bslot*256 + threadIdx.x; e < N_EDGES; e += stride){
    int d = ei[N_EDGES + e];
    if (d >= lo && d < hi){
      int pos = atomicAdd(&cnt[d], 1);
      if (pos < CAP){
        uint32_t wb = __float_as_uint(ew[e]);
        uint32_t wenc = ((wb + 0x8000u) >> 16) & 0x7FFFu;
        eslot[(size_t)d*CAP + pos] = (uint32_t)ei[e] | (wenc << 17);
      } else {
        int oi = atomicAdd(&cnt[N_NODES], 1);
        ovf[oi] = e;
      }
    }
  }
}

// ---------------- gather: node-per-wave, register accumulate, 8-deep MLP unroll ----
__global__ __launch_bounds__(256) void k_gather(const int* __restrict__ cnt,
                         const uint32_t* __restrict__ eslot,
                         const uint32_t* __restrict__ elwb, const float* __restrict__ elb,
                         const int* __restrict__ ei, const float* __restrict__ ew,
                         const int* __restrict__ ovf,
                         uint32_t* __restrict__ accbb){
  int wid = (blockIdx.x * blockDim.x + threadIdx.x) >> 6;
  int lane = threadIdx.x & 63;
  if (wid >= N_NODES) return;
  const uint32_t* base = eslot + (size_t)wid*CAP;
  int c = cnt[wid];
  int cc = min(c, CAP);
  float sx = 0.f, sy = 0.f;
  int e = 0;
  for (; e + 8 <= cc; e += 8){
    uint32_t p0 = base[e],   p1 = base[e+1], p2 = base[e+2], p3 = base[e+3];
    uint32_t p4 = base[e+4], p5 = base[e+5], p6 = base[e+6], p7 = base[e+7];
    uint32_t u0 = elwb[(size_t)(p0 & 0x1FFFFu)*(HD/2) + lane];
    uint32_t u1 = elwb[(size_t)(p1 & 0x1FFFFu)*(HD/2) + lane];
    uint32_t u2 = elwb[(size_t)(p2 & 0x1FFFFu)*(HD/2) + lane];
    uint32_t u3 = elwb[(size_t)(p3 & 0x1FFFFu)*(HD/2) + lane];
    uint32_t u4 = elwb[(size_t)(p4 & 0x1FFFFu)*(HD/2) + lane];
    uint32_t u5 = elwb[(size_t)(p5 & 0x1FFFFu)*(HD/2) + lane];
    uint32_t u6 = elwb[(size_t)(p6 & 0x1FFFFu)*(HD/2) + lane];
    uint32_t u7 = elwb[(size_t)(p7 & 0x1FFFFu)*(HD/2) + lane];
    float w0 = __uint_as_float((p0 >> 17) << 16), w1 = __uint_as_float((p1 >> 17) << 16);
    float w2 = __uint_as_float((p2 >> 17) << 16), w3 = __uint_as_float((p3 >> 17) << 16);
    float w4 = __uint_as_float((p4 >> 17) << 16), w5 = __uint_as_float((p5 >> 17) << 16);
    float w6 = __uint_as_float((p6 >> 17) << 16), w7 = __uint_as_float((p7 >> 17) << 16);
    sx += __uint_as_float(u0 << 16) * w0;  sy += __uint_as_float(u0 & 0xFFFF0000u) * w0;
    sx += __uint_as_float(u1 << 16) * w1;  sy += __uint_as_float(u1 & 0xFFFF0000u) * w1;
    sx += __uint_as_float(u2 << 16) * w2;  sy += __uint_as_float(u2 & 0xFFFF0000u) * w2;
    sx += __uint_as_float(u3 << 16) * w3;  sy += __uint_as_float(u3 & 0xFFFF0000u) * w3;
    sx += __uint_as_float(u4 << 16) * w4;  sy += __uint_as_float(u4 & 0xFFFF0000u) * w4;
    sx += __uint_as_float(u5 << 16) * w5;  sy += __uint_as_float(u5 & 0xFFFF0000u) * w5;
    sx += __uint_as_float(u6 << 16) * w6;  sy += __uint_as_float(u6 & 0xFFFF0000u) * w6;
    sx += __uint_as_float(u7 << 16) * w7;  sy += __uint_as_float(u7 & 0xFFFF0000u) * w7;
  }
  for (; e < cc; ++e){
    uint32_t p = base[e];
    float wv = __uint_as_float((p >> 17) << 16);
    uint32_t u = elwb[(size_t)(p & 0x1FFFFu)*(HD/2) + lane];
    sx += __uint_as_float(u << 16) * wv;
    sy += __uint_as_float(u & 0xFFFF0000u) * wv;
  }
  if (c > CAP){
    // overflow fallback (statistically never; strict correctness)
    int ocnt = cnt[N_NODES];
    for (int i = 0; i < ocnt; ++i){
      int ee = ovf[i];
      if (ei[N_EDGES + ee] == wid){
        float wv = ew[ee];
        uint32_t u = elwb[(size_t)ei[ee]*(HD/2) + lane];
        sx += __uint_as_float(u << 16) * wv;
        sy += __uint_as_float(u & 0xFFFF0000u) * wv;
      }
    }
  }
  sx += elb[lane*2]; sy += elb[lane*2+1];
  accbb[(size_t)wid*(HD/2) + lane] = bf16rne(sx) | (bf16rne(sy) << 16);
}

// ---------------- fused node chain via bf16 MFMA, hi/lo compensated A ----------------
__global__ __launch_bounds__(512, 4) void k_fused(
    const uint32_t* __restrict__ accbb, const float* __restrict__ x,
    const uint32_t* __restrict__ B1pk, const uint32_t* __restrict__ B2pk,
    const uint32_t* __restrict__ B3pk, const uint32_t* __restrict__ B4pk,
    const float* __restrict__ biasv, const float* __restrict__ sb0,
    const float* __restrict__ sb1, float* __restrict__ outp){
  __shared__ uint32_t lds[16384];                 // 64 KB
  short* sHi = (short*)lds;
  short* sLo = sHi + 16384;
  const int tid = threadIdx.x;
  const int lane = tid & 63, wid = tid >> 6;
  const int l15 = lane & 15, l4 = lane >> 4;
  const int wr = wid >> 2, wc = wid & 3;
  const int row0 = blockIdx.x * HD;

  #pragma unroll
  for (int p=0;p<4;p++){
    int idx = tid + p*512;
    int r = idx >> 4, slot = idx & 15;
    uint4 v = make_uint4(0,0,0,0);
    if (row0 + r < N_NODES) v = ((const uint4*)accbb)[(size_t)(row0+r)*16 + slot];
    *(uint4*)&sHi[r*128 + ((slot ^ (r & 15)) << 3)] = v;
  }
  __syncthreads();

  f32x4 acc[4][2];
  #pragma unroll
  for (int rt=0;rt<4;rt++)
    #pragma unroll
    for (int ct=0;ct<2;ct++) acc[rt][ct] = (f32x4){0.f,0.f,0.f,0.f};
  #pragma unroll
  for (int kt=0;kt<4;kt++){
    int aslot = ((kt*4 + l4) ^ l15) << 3;
    bf16x8 b0 = ((const bf16x8*)B1pk)[((wc*2+0)*4 + kt)*64 + lane];
    bf16x8 b1 = ((const bf16x8*)B1pk)[((wc*2+1)*4 + kt)*64 + lane];
    #pragma unroll
    for (int rt=0;rt<4;rt++){
      bf16x8 a = *(const bf16x8*)&sHi[(wr*64 + rt*16 + l15)*128 + aslot];
      acc[rt][0] = __builtin_amdgcn_mfma_f32_16x16x32_bf16(a, b0, acc[rt][0], 0,0,0);
      acc[rt][1] = __builtin_amdgcn_mfma_f32_16x16x32_bf16(a, b1, acc[rt][1], 0,0,0);
    }
  }
  __syncthreads();

  #pragma unroll
  for (int p=0;p<8;p++){
    int idx = tid + p*512;
    int r = idx >> 5, half = idx & 31;
    int slot = half >> 1, h4 = (half & 1) * 4;
    float4 v = make_float4(0.f,0.f,0.f,0.f);
    if (row0 + r < N_NODES) v = ((const float4*)x)[(size_t)(row0+r)*32 + half];
    uint hx = bf16rne(v.x), hy = bf16rne(v.y), hz = bf16rne(v.z), hw = bf16rne(v.w);
    uint lx = bf16rne(v.x - __uint_as_float(hx<<16));
    uint ly = bf16rne(v.y - __uint_as_float(hy<<16));
    uint lz = bf16rne(v.z - __uint_as_float(hz<<16));
    uint lw = bf16rne(v.w - __uint_as_float(hw<<16));
    int base = r*128 + ((slot ^ (r & 15)) << 3) + h4;
    *(uint2*)&sHi[base] = make_uint2(hx | (hy<<16), hz | (hw<<16));
    *(uint2*)&sLo[base] = make_uint2(lx | (ly<<16), lz | (lw<<16));
  }
  __syncthreads();

  #pragma unroll
  for (int kt=0;kt<4;kt++){
    int aslot = ((kt*4 + l4) ^ l15) << 3;
    bf16x8 b0 = ((const bf16x8*)B2pk)[((wc*2+0)*4 + kt)*64 + lane];
    bf16x8 b1 = ((const bf16x8*)B2pk)[((wc*2+1)*4 + kt)*64 + lane];
    #pragma unroll
    for (int rt=0;rt<4;rt++){
      int abase = (wr*64 + rt*16 + l15)*128 + aslot;
      bf16x8 ah = *(const bf16x8*)&sHi[abase];
      bf16x8 al = *(const bf16x8*)&sLo[abase];
      acc[rt][0] = __builtin_amdgcn_mfma_f32_16x16x32_bf16(ah, b0, acc[rt][0], 0,0,0);
      acc[rt][1] = __builtin_amdgcn_mfma_f32_16x16x32_bf16(ah, b1, acc[rt][1], 0,0,0);
      acc[rt][0] = __builtin_amdgcn_mfma_f32_16x16x32_bf16(al, b0, acc[rt][0], 0,0,0);
      acc[rt][1] = __builtin_amdgcn_mfma_f32_16x16x32_bf16(al, b1, acc[rt][1], 0,0,0);
    }
  }
  __syncthreads();

  #pragma unroll
  for (int ct=0;ct<2;ct++){
    int col = wc*32 + ct*16 + l15;
    float bb = biasv[col];
    int slotE = (col >> 3), elem = col & 7;
    #pragma unroll
    for (int rt=0;rt<4;rt++)
      #pragma unroll
      for (int rg=0;rg<4;rg++){
        int r = wr*64 + rt*16 + l4*4 + rg;
        float v = lrelu(acc[rt][ct][rg] + bb);
        uint h = bf16rne(v);
        uint l = bf16rne(v - __uint_as_float(h<<16));
        int sa = r*128 + ((slotE ^ (r & 15)) << 3) + elem;
        sHi[sa] = (short)h; sLo[sa] = (short)l;
      }
  }
  __syncthreads();

  #pragma unroll
  for (int rt=0;rt<4;rt++)
    #pragma unroll
    for (int ct=0;ct<2;ct++) acc[rt][ct] = (f32x4){0.f,0.f,0.f,0.f};
  #pragma unroll
  for (int kt=0;kt<4;kt++){
    int aslot = ((kt*4 + l4) ^ l15) << 3;
    bf16x8 b0 = ((const bf16x8*)B3pk)[((wc*2+0)*4 + kt)*64 + lane];
    bf16x8 b1 = ((const bf16x8*)B3pk)[((wc*2+1)*4 + kt)*64 + lane];
    #pragma unroll
    for (int rt=0;rt<4;rt++){
      int abase = (wr*64 + rt*16 + l15)*128 + aslot;
      bf16x8 ah = *(const bf16x8*)&sHi[abase];
      bf16x8 al = *(const bf16x8*)&sLo[abase];
      acc[rt][0] = __builtin_amdgcn_mfma_f32_16x16x32_bf16(ah, b0, acc[rt][0], 0,0,0);
      acc[rt][1] = __builtin_amdgcn_mfma_f32_16x16x32_bf16(ah, b1, acc[rt][1], 0,0,0);
      acc[rt][0] = __builtin_amdgcn_mfma_f32_16x16x32_bf16(al, b0, acc[rt][0], 0,0,0);
      acc[rt][1] = __builtin_amdgcn_mfma_f32_16x16x32_bf16(al, b1, acc[rt][1], 0,0,0);
    }
  }
  __syncthreads();

  #pragma unroll
  for (int ct=0;ct<2;ct++){
    int col = wc*32 + ct*16 + l15;
    float bb = sb0[col];
    int slotE = (col >> 3), elem = col & 7;
    #pragma unroll
    for (int rt=0;rt<4;rt++)
      #pragma unroll
      for (int rg=0;rg<4;rg++){
        int r = wr*64 + rt*16 + l4*4 + rg;
        float v = lrelu(acc[rt][ct][rg] + bb);
        uint h = bf16rne(v);
        uint l = bf16rne(v - __uint_as_float(h<<16));
        int sa = r*128 + ((slotE ^ (r & 15)) << 3) + elem;
        sHi[sa] = (short)h; sLo[sa] = (short)l;
      }
  }
  __syncthreads();

  f32x4 y[4];
  #pragma unroll
  for (int ct=0;ct<4;ct++) y[ct] = (f32x4){0.f,0.f,0.f,0.f};
  #pragma unroll
  for (int kt=0;kt<4;kt++){
    int abase = (wid*16 + l15)*128 + (((kt*4 + l4) ^ l15) << 3);
    bf16x8 ah = *(const bf16x8*)&sHi[abase];
    bf16x8 al = *(const bf16x8*)&sLo[abase];
    #pragma unroll
    for (int ct=0;ct<4;ct++){
      bf16x8 b = ((const bf16x8*)B4pk)[(ct*4 + kt)*64 + lane];
      y[ct] = __builtin_amdgcn_mfma_f32_16x16x32_bf16(ah, b, y[ct], 0,0,0);
      y[ct] = __builtin_amdgcn_mfma_f32_16x16x32_bf16(al, b, y[ct], 0,0,0);
    }
  }
  __syncthreads();

  float* sOut = (float*)lds;
  #pragma unroll
  for (int ct=0;ct<4;ct++){
    int col = ct*16 + l15;
    float bb = sb1[col];
    #pragma unroll
    for (int rg=0;rg<4;rg++){
      int r = wid*16 + l4*4 + rg;
      sOut[r*OUTC + col] = lrelu(y[ct][rg] + bb);
    }
  }
  __syncthreads();
  #pragma unroll
  for (int p=0;p<4;p++){
    int o = tid + p*512;
    int r = o >> 4;
    if (row0 + r < N_NODES)
      ((float4*)outp)[(size_t)(row0+r)*16 + (o & 15)] = ((const float4*)sOut)[o];
  }
}

extern "C" void kernel_launch(void* const* d_in, const int* in_sizes, int n_in,
                              void* d_out, int out_size, void* d_ws, size_t ws_size,
                              hipStream_t stream){
  const float* x      = (const float*)d_in[0];
  const int*   ei     = (const int*)d_in[1];
  const float* ew     = (const float*)d_in[2];
  const float* w      = (const float*)d_in[3];
  const float* elw    = (const float*)d_in[4];
  const float* elb    = (const float*)d_in[5];
  const float* node_w = (const float*)d_in[6];
  const float* node_b = (const float*)d_in[7];
  const float* cat1_w = (const float*)d_in[8];
  const float* cat1_b = (const float*)d_in[9];
  const float* cat2_w = (const float*)d_in[10];
  const float* cat2_b = (const float*)d_in[11];
  const float* a0w    = (const float*)d_in[12];
  const float* a0b    = (const float*)d_in[13];
  const float* syn0_w = (const float*)d_in[14];
  const float* syn0_b = (const float*)d_in[15];
  const float* a1w    = (const float*)d_in[16];
  const float* a1b    = (const float*)d_in[17];
  const float* syn1_w = (const float*)d_in[18];
  const float* syn1_b = (const float*)d_in[19];
  float* outp = (float*)d_out;

  uint32_t* wsu = (uint32_t*)d_ws;
  uint32_t* accbb = wsu;                                   // N*64 u32 (25.6MB)
  uint32_t* elwb  = accbb + (size_t)N_NODES*(HD/2);        // N*64 u32 (25.6MB)
  uint32_t* eslot = elwb + (size_t)N_NODES*(HD/2);         // N*CAP u32 (25.6MB)
  float* st0    = (float*)(eslot + (size_t)N_NODES*CAP);   // 2560
  float* st1    = st0 + 2560;                              // 1920
  float* M2     = st1 + 1920;                              // 128*128
  float* biasv  = M2 + HD*HD;                              // 128
  float* W0T    = biasv + HD;                              // 128*128
  float* W1T    = W0T + HD*HD;                             // 128*64
  uint32_t* B1pk = (uint32_t*)(W1T + HD*OUTC);             // 8192 u32
  uint32_t* B2pk = B1pk + 8192;
  uint32_t* B3pk = B2pk + 8192;
  uint32_t* B4pk = B3pk + 8192;                            // 4096 u32
  int*   cnt    = (int*)(B4pk + 4096);                     // N+1 (last = ovf count)
  int*   ovf    = cnt + N_NODES + 1;                       // overflow edge ids

  hipMemsetAsync(cnt, 0, (N_NODES+1)*sizeof(int), stream);
  k_cvt<<<(N_NODES*(HD/2)+255)/256, 256, 0, stream>>>(elw, elwb);
  k_styles<<<(2560+1920+255)/256, 256, 0, stream>>>(w, a0w, a0b, a1w, a1b, st0, st1);
  k_wmod<<<HD, HD, 0, stream>>>(st0, syn0_w, W0T, HD);
  k_wmod<<<OUTC, HD, 0, stream>>>(st1, syn1_w, W1T, OUTC);
  k_m2bias<<<HD+1, HD, 0, stream>>>(node_w, node_b, cat2_w, cat1_b, cat2_b, M2, biasv);
  k_pack<<<32, 64, 0, stream>>>(cat1_w, HD, HD, 1, B1pk);
  k_pack<<<32, 64, 0, stream>>>(M2,    HD, HD, 0, B2pk);
  k_pack<<<32, 64, 0, stream>>>(W0T,   HD, HD, 0, B3pk);
  k_pack<<<16, 64, 0, stream>>>(W1T,   HD, OUTC, 0, B4pk);
  k_fill<<<FILL_BLOCKS, 256, 0, stream>>>(ei, ew, cnt, eslot, ovf);
  k_gather<<<(N_NODES*64)/256, 256, 0, stream>>>(cnt, eslot, elwb, elb, ei, ew, ovf, accbb);
  k_fused<<<(N_NODES+HD-1)/HD, 512, 0, stream>>>(accbb, x, B1pk, B2pk, B3pk, B4pk,
                                                 biasv, syn0_b, syn1_b, outp);
}